// Round 3
// baseline (295.079 us; speedup 1.0000x reference)
//
#include <hip/hip_runtime.h>
#include <hip/hip_bf16.h>
#include <stdint.h>

// Problem constants (reference: B=2, D=128, H=64, W=64)
#define BN 2
#define DN 128
#define MN 4096                 // H*W pixels per image
#define TOTAL_INV (1.0f / 33554432.0f)   // 1 / (B*M*N)

typedef __attribute__((ext_vector_type(8))) short short8;   // 8 bf16 = 4 VGPRs
typedef __attribute__((ext_vector_type(4))) float f32x4;

__device__ static inline unsigned short f2bf(float x) {
  unsigned int u = __float_as_uint(x);
  u += 0x7fffu + ((u >> 16) & 1u);      // RNE f32 -> bf16
  return (unsigned short)(u >> 16);
}

// [B, D, M] f32 -> [B, M, D] bf16; also zeroes out[0] (d_out re-poisoned 0xAA)
__global__ __launch_bounds__(256) void transpose_cvt(
    const float* __restrict__ s0, const float* __restrict__ s1,
    unsigned short* __restrict__ o0, unsigned short* __restrict__ o1,
    float* __restrict__ outp) {
  if (threadIdx.x == 0 && blockIdx.x == 0 && blockIdx.y == 0 && blockIdx.z == 0)
    *outp = 0.0f;   // gemm_loss launches after us on the same stream
  __shared__ float tile[64][65];
  const int tx = threadIdx.x & 63;
  const int ty = threadIdx.x >> 6;
  const int m0 = blockIdx.x * 64;
  const int d0 = blockIdx.y * 64;
  const int b  = blockIdx.z & 1;
  const float* src = (blockIdx.z >> 1) ? s1 : s0;
  unsigned short* dst = (blockIdx.z >> 1) ? o1 : o0;
  src += (size_t)b * DN * MN;
  dst += (size_t)b * MN * DN;
#pragma unroll
  for (int i = 0; i < 16; ++i) {
    int dr = i * 4 + ty;
    tile[dr][tx] = src[(size_t)(d0 + dr) * MN + m0 + tx];
  }
  __syncthreads();
#pragma unroll
  for (int i = 0; i < 16; ++i) {
    int mr = i * 4 + ty;
    dst[(size_t)(m0 + mr) * DN + d0 + tx] = f2bf(tile[tx][mr]);
  }
}

// Fused bf16 MFMA GEMM (C = A * B^T) + hinge loss + mean.
// grid (N/128, M/128, B), block 256 = 4 waves in 2x2; each wave owns an
// INDEPENDENT 64x64 output tile. No LDS, no __syncthreads: fragments are
// loaded straight global->VGPR (A/B total 4 MB, L2/L3-resident), mask read
// per-element in the epilogue. Latency hidden by TLP (12+ waves/CU).
__global__ __launch_bounds__(256, 3) void gemm_loss(
    const unsigned short* __restrict__ A, const unsigned short* __restrict__ Bm,
    const void* __restrict__ maskp, float* __restrict__ out) {
  const int tid  = threadIdx.x;
  const int lane = tid & 63;
  const int wave = tid >> 6;
  const int wm = wave >> 1, wn = wave & 1;
  const int quad = lane >> 4;
  const int l16  = lane & 15;
  const int bz = blockIdx.z;
  const int gm = blockIdx.y * 128 + wm * 64;   // wave-tile origin (rows of A)
  const int gn = blockIdx.x * 128 + wn * 64;   // wave-tile origin (rows of B)

  // mask dtype sniff (wave-uniform, no barrier): i32 {0,1} has zero high bytes
  unsigned sw = ((const unsigned int*)maskp)[lane];
  const bool mask_u8 = (__ballot((sw & 0xFFFFFF00u) != 0u) != 0ull);

  const unsigned short* Ab = A  + (size_t)bz * MN * DN + (size_t)gm * DN;
  const unsigned short* Bb = Bm + (size_t)bz * MN * DN + (size_t)gn * DN;

  f32x4 acc[4][4];
#pragma unroll
  for (int i = 0; i < 4; ++i)
#pragma unroll
    for (int j = 0; j < 4; ++j) acc[i][j] = (f32x4){0.f, 0.f, 0.f, 0.f};

  // K = 128 in 4 chunks of 32. unroll 1 keeps frags-in-flight at one kt
  // (~32 VGPR) so occupancy stays high; TLP covers the per-kt load latency.
#pragma unroll 1
  for (int kt = 0; kt < 4; ++kt) {
    const int k0 = kt * 32 + quad * 8;   // per-lane k offset (16B aligned)
    short8 af[4], bf[4];
#pragma unroll
    for (int mi = 0; mi < 4; ++mi)   // global_load_dwordx4, rows stride 256B
      af[mi] = *(const short8*)(Ab + (size_t)(mi * 16 + l16) * DN + k0);
#pragma unroll
    for (int ni = 0; ni < 4; ++ni)
      bf[ni] = *(const short8*)(Bb + (size_t)(ni * 16 + l16) * DN + k0);
#pragma unroll
    for (int mi = 0; mi < 4; ++mi)
#pragma unroll
      for (int ni = 0; ni < 4; ++ni)
        acc[mi][ni] = __builtin_amdgcn_mfma_f32_16x16x32_bf16(
            af[mi], bf[ni], acc[mi][ni], 0, 0, 0);
  }

  // ---- epilogue: hinge loss under mask, wave reduce, one atomic per wave.
  // C/D layout: col = lane&15 (n), row = quad*4 + r (m)
  const size_t mbase = ((size_t)bz * MN + (size_t)gm) * MN + (size_t)gn;
  const int* mi32 = (const int*)maskp;
  const unsigned char* mu8 = (const unsigned char*)maskp;
  float lsum = 0.0f;
#pragma unroll
  for (int mi = 0; mi < 4; ++mi) {
#pragma unroll
    for (int ni = 0; ni < 4; ++ni) {
      f32x4 v = acc[mi][ni];
#pragma unroll
      for (int r = 0; r < 4; ++r) {
        int m = mi * 16 + quad * 4 + r;
        int n = ni * 16 + l16;
        size_t idx = mbase + (size_t)m * MN + n;
        int msk = mask_u8 ? (int)mu8[idx] : mi32[idx];
        float dot = v[r];
        float pos = fmaxf(0.0f, 1.0f - dot) * 250.0f;
        float neg = fmaxf(0.0f, dot - 0.2f);
        lsum += msk ? pos : neg;
      }
    }
  }
#pragma unroll
  for (int off = 32; off > 0; off >>= 1) lsum += __shfl_xor(lsum, off);
  if (lane == 0) atomicAdd(out, lsum * TOTAL_INV);   // 4 atomics/block
}

extern "C" void kernel_launch(void* const* d_in, const int* in_sizes, int n_in,
                              void* d_out, int out_size, void* d_ws, size_t ws_size,
                              hipStream_t stream) {
  const float* d0 = (const float*)d_in[0];
  const float* d1 = (const float*)d_in[1];
  const void* mask = d_in[2];
  float* out = (float*)d_out;

  unsigned short* Aw = (unsigned short*)d_ws;            // [B, M, D] bf16, 2 MB
  unsigned short* Bw = Aw + (size_t)BN * MN * DN;        // [B, M, D] bf16, 2 MB

  dim3 g1(MN / 64, DN / 64, BN * 2), b1(256);
  transpose_cvt<<<g1, b1, 0, stream>>>(d0, d1, Aw, Bw, out);

  dim3 g2(MN / 128, MN / 128, BN), b2(256);
  gemm_loss<<<g2, b2, 0, stream>>>(Aw, Bw, mask, out);
}

// Round 4
// 233.936 us; speedup vs baseline: 1.2614x; 1.2614x over previous
//
#include <hip/hip_runtime.h>
#include <hip/hip_bf16.h>
#include <stdint.h>

// Problem constants (reference: B=2, D=128, H=64, W=64)
#define BN 2
#define DN 128
#define MN 4096                 // H*W pixels per image
#define TOTAL_INV (1.0f / 33554432.0f)   // 1 / (B*M*N)
#define NPART 8192              // 2048 blocks x 4 waves

typedef __attribute__((ext_vector_type(8))) short short8;   // 8 bf16 = 4 VGPRs
typedef __attribute__((ext_vector_type(4))) float f32x4;

__device__ static inline unsigned short f2bf(float x) {
  unsigned int u = __float_as_uint(x);
  u += 0x7fffu + ((u >> 16) & 1u);      // RNE f32 -> bf16
  return (unsigned short)(u >> 16);
}

// [B, D, M] f32 -> [B, M, D] bf16
__global__ __launch_bounds__(256) void transpose_cvt(
    const float* __restrict__ s0, const float* __restrict__ s1,
    unsigned short* __restrict__ o0, unsigned short* __restrict__ o1) {
  __shared__ float tile[64][65];
  const int tx = threadIdx.x & 63;
  const int ty = threadIdx.x >> 6;
  const int m0 = blockIdx.x * 64;
  const int d0 = blockIdx.y * 64;
  const int b  = blockIdx.z & 1;
  const float* src = (blockIdx.z >> 1) ? s1 : s0;
  unsigned short* dst = (blockIdx.z >> 1) ? o1 : o0;
  src += (size_t)b * DN * MN;
  dst += (size_t)b * MN * DN;
#pragma unroll
  for (int i = 0; i < 16; ++i) {
    int dr = i * 4 + ty;
    tile[dr][tx] = src[(size_t)(d0 + dr) * MN + m0 + tx];
  }
  __syncthreads();
#pragma unroll
  for (int i = 0; i < 16; ++i) {
    int mr = i * 4 + ty;
    dst[(size_t)(m0 + mr) * DN + d0 + tx] = f2bf(tile[tx][mr]);
  }
}

// Fused bf16 MFMA GEMM (C = A * B^T) + hinge loss + partial sums.
// grid (N/128, M/128, B), block 256 = 4 waves in 2x2; each wave owns an
// independent 64x64 output tile. No LDS, no __syncthreads, NO atomics:
// each wave stores its partial to part[] (contention-free), reduced later.
__global__ __launch_bounds__(256, 3) void gemm_loss(
    const unsigned short* __restrict__ A, const unsigned short* __restrict__ Bm,
    const void* __restrict__ maskp, float* __restrict__ part) {
  const int tid  = threadIdx.x;
  const int lane = tid & 63;
  const int wave = tid >> 6;
  const int wm = wave >> 1, wn = wave & 1;
  const int quad = lane >> 4;
  const int l16  = lane & 15;
  const int bz = blockIdx.z;
  const int gm = blockIdx.y * 128 + wm * 64;   // wave-tile origin (rows of A)
  const int gn = blockIdx.x * 128 + wn * 64;   // wave-tile origin (rows of B)

  // mask dtype sniff (wave-uniform, no barrier): i32 {0,1} has zero high bytes
  unsigned sw = ((const unsigned int*)maskp)[lane];
  const bool mask_u8 = (__ballot((sw & 0xFFFFFF00u) != 0u) != 0ull);

  const unsigned short* Ab = A  + (size_t)bz * MN * DN + (size_t)gm * DN;
  const unsigned short* Bb = Bm + (size_t)bz * MN * DN + (size_t)gn * DN;

  f32x4 acc[4][4];
#pragma unroll
  for (int i = 0; i < 4; ++i)
#pragma unroll
    for (int j = 0; j < 4; ++j) acc[i][j] = (f32x4){0.f, 0.f, 0.f, 0.f};

#pragma unroll 1
  for (int kt = 0; kt < 4; ++kt) {
    const int k0 = kt * 32 + quad * 8;   // per-lane k offset (16B aligned)
    short8 af[4], bf[4];
#pragma unroll
    for (int mi = 0; mi < 4; ++mi)   // global_load_dwordx4, rows stride 256B
      af[mi] = *(const short8*)(Ab + (size_t)(mi * 16 + l16) * DN + k0);
#pragma unroll
    for (int ni = 0; ni < 4; ++ni)
      bf[ni] = *(const short8*)(Bb + (size_t)(ni * 16 + l16) * DN + k0);
#pragma unroll
    for (int mi = 0; mi < 4; ++mi)
#pragma unroll
      for (int ni = 0; ni < 4; ++ni)
        acc[mi][ni] = __builtin_amdgcn_mfma_f32_16x16x32_bf16(
            af[mi], bf[ni], acc[mi][ni], 0, 0, 0);
  }

  // ---- epilogue: hinge loss under mask, wave reduce, ONE STORE per wave.
  // C/D layout: col = lane&15 (n), row = quad*4 + r (m)
  const size_t mbase = ((size_t)bz * MN + (size_t)gm) * MN + (size_t)gn;
  const int* mi32 = (const int*)maskp;
  const unsigned char* mu8 = (const unsigned char*)maskp;
  float lsum = 0.0f;
#pragma unroll
  for (int mi = 0; mi < 4; ++mi) {
#pragma unroll
    for (int ni = 0; ni < 4; ++ni) {
      f32x4 v = acc[mi][ni];
#pragma unroll
      for (int r = 0; r < 4; ++r) {
        int m = mi * 16 + quad * 4 + r;
        int n = ni * 16 + l16;
        size_t idx = mbase + (size_t)m * MN + n;
        int msk = mask_u8 ? (int)mu8[idx] : mi32[idx];
        float dot = v[r];
        float pos = fmaxf(0.0f, 1.0f - dot) * 250.0f;
        float neg = fmaxf(0.0f, dot - 0.2f);
        lsum += msk ? pos : neg;
      }
    }
  }
#pragma unroll
  for (int off = 32; off > 0; off >>= 1) lsum += __shfl_xor(lsum, off);
  if (lane == 0) {
    size_t slot =
        (((size_t)bz * gridDim.y + blockIdx.y) * gridDim.x + blockIdx.x) * 4 + wave;
    part[slot] = lsum;                      // contention-free store
  }
}

// Sum 8192 partials -> out[0]. One block; overwrites out (no pre-zero needed).
__global__ __launch_bounds__(1024) void reduce_partials(
    const float* __restrict__ part, float* __restrict__ out) {
  float s = 0.0f;
#pragma unroll
  for (int i = 0; i < NPART / 1024; ++i) s += part[threadIdx.x + i * 1024];
#pragma unroll
  for (int off = 32; off > 0; off >>= 1) s += __shfl_xor(s, off);
  __shared__ float red[16];
  if ((threadIdx.x & 63) == 0) red[threadIdx.x >> 6] = s;
  __syncthreads();
  if (threadIdx.x == 0) {
    float t = 0.0f;
#pragma unroll
    for (int i = 0; i < 16; ++i) t += red[i];
    *out = t * TOTAL_INV;
  }
}

extern "C" void kernel_launch(void* const* d_in, const int* in_sizes, int n_in,
                              void* d_out, int out_size, void* d_ws, size_t ws_size,
                              hipStream_t stream) {
  const float* d0 = (const float*)d_in[0];
  const float* d1 = (const float*)d_in[1];
  const void* mask = d_in[2];
  float* out = (float*)d_out;

  unsigned short* Aw = (unsigned short*)d_ws;            // [B, M, D] bf16, 2 MB
  unsigned short* Bw = Aw + (size_t)BN * MN * DN;        // [B, M, D] bf16, 2 MB
  float* part = (float*)(Bw + (size_t)BN * MN * DN);     // 8192 f32, 32 KB

  dim3 g1(MN / 64, DN / 64, BN * 2), b1(256);
  transpose_cvt<<<g1, b1, 0, stream>>>(d0, d1, Aw, Bw);

  dim3 g2(MN / 128, MN / 128, BN), b2(256);
  gemm_loss<<<g2, b2, 0, stream>>>(Aw, Bw, mask, part);

  reduce_partials<<<1, 1024, 0, stream>>>(part, out);
}